// Round 7
// baseline (163.496 us; speedup 1.0000x reference)
//
#include <hip/hip_runtime.h>

#define NN 128
#define TT 256
#define EE 6
#define DD 10
#define TE (TT*EE)          // 1536
#define C1 15               // input1 inner dim: 1+E+E+2

typedef float f32x4 __attribute__((ext_vector_type(4)));
typedef const __attribute__((address_space(1))) void g_void;
typedef __attribute__((address_space(3))) void l_void;

// Fused pair kernel: each wave owns 4 tiles (i0..i0+3, j) = 24 KB of yij stream.
// yij is streamed via global_load_lds (HBM -> LDS DMA, bypassing the VGPR-return
// read path) into a per-wave-private 6 KB LDS buffer; w[j] and yi[j] live in
// registers. No __syncthreads anywhere (LDS partitioned per wave).
__global__ __launch_bounds__(256) void pair_all(const float* __restrict__ yij,
                                                const float* __restrict__ yi,
                                                const float* __restrict__ input1,
                                                float* __restrict__ raw,
                                                float* __restrict__ out) {
    const int bid  = blockIdx.x;            // 0..1023
    const int tid  = threadIdx.x;
    const int lane = tid & 63;
    const int wv   = tid >> 6;
    const int j    = bid & (NN - 1);
    const int i0   = (bid >> 7) * 16 + wv * 4;     // {0,4,...,124}

    if (bid == 0 && tid == 0) out[0] = 0.0f;       // finalize runs in a later dispatch

    __shared__ __attribute__((aligned(16))) float lbuf[4 * TE];   // 24 KB, 6 KB/wave
    float* myb = lbuf + wv * TE;

    // Register prologue: this lane's 24 slots are float indices 4*lane + c + 256*k.
    f32x4 wj[6], mj[6];
    const float* __restrict__ i1 = input1 + (size_t)j * TT * C1 + 1 + EE;  // [t*C1 + e]
#pragma unroll
    for (int k = 0; k < 6; ++k) {
        mj[k] = *(const f32x4*)(yi + (size_t)j * TE + 4 * lane + 256 * k);
        f32x4 t;
#pragma unroll
        for (int c = 0; c < 4; ++c) {
            const int idx = 4 * lane + c + 256 * k;        // < 1536
            const int tt  = idx / EE, e = idx - tt * EE;   // const-div -> magic mul
            const float v = i1[tt * C1 + e];
            t[c] = 1.0f / (v * v);
        }
        wj[k] = t;
    }

    // Stream 4 tiles of 6 KB each through the LDS-DMA path.
    float accs[4];
#pragma unroll
    for (int p = 0; p < 4; ++p) {
        const float* base = yij + ((size_t)(i0 + p) * NN + j) * TE;
        // Issue 6 x global_load_lds: per-lane 16B from global, LDS dest =
        // wave-uniform base + lane*16 (linear layout, matches read-back below).
#pragma unroll
        for (int k = 0; k < 6; ++k) {
            __builtin_amdgcn_global_load_lds((g_void*)(base + 4 * lane + 256 * k),
                                             (l_void*)(myb + 256 * k),
                                             16, 0, 0);
        }
        asm volatile("s_waitcnt vmcnt(0)" ::: "memory");   // wave-private drain
        __builtin_amdgcn_sched_barrier(0);

        float s0 = 0.0f, s1 = 0.0f, s2 = 0.0f, s3 = 0.0f;
#pragma unroll
        for (int k = 0; k < 6; ++k) {
            f32x4 x = *(const f32x4*)(myb + 4 * lane + 256 * k);   // ds_read_b128
            float d0 = x.x - mj[k].x; s0 += d0 * d0 * wj[k].x;
            float d1 = x.y - mj[k].y; s1 += d1 * d1 * wj[k].y;
            float d2 = x.z - mj[k].z; s2 += d2 * d2 * wj[k].z;
            float d3 = x.w - mj[k].w; s3 += d3 * d3 * wj[k].w;
        }
        accs[p] = (s0 + s1) + (s2 + s3);
        // All ds_reads are consumed by the FMAs above (lgkmcnt drained by use)
        // before the next tile's DMA can overwrite the buffer (~900cy later).
    }

#pragma unroll
    for (int p = 0; p < 4; ++p) {
        float s = accs[p];
#pragma unroll
        for (int off = 32; off > 0; off >>= 1) s += __shfl_down(s, off);
        if (lane == 0) raw[(i0 + p) * NN + j] = s;
    }
}

// Kernel 2: L = mean_{i,j} | S_ij - 0.5*(sec[i,j]+sec[j,i]) |
// 64 blocks x 256 threads; one scaled atomicAdd per block (out pre-zeroed by pair_all).
__global__ __launch_bounds__(256) void finalize(const float* __restrict__ raw,
                                                const float* __restrict__ samples,
                                                float* __restrict__ out) {
    __shared__ float smp[DD * NN];     // transposed: smp[d*NN + n], stride-1 reads
    for (int k = threadIdx.x; k < NN * DD; k += 256) {
        int n = k / DD, d = k % DD;
        smp[d * NN + n] = samples[k];
    }
    __syncthreads();

    const int p = blockIdx.x * 256 + threadIdx.x;   // 0..16383
    const int i = p >> 7, j = p & (NN - 1);

    float S = 0.0f;
#pragma unroll
    for (int d = 0; d < DD; ++d) {
        float dd = smp[d * NN + j] - smp[d * NN + i];
        S += dd * dd;
    }
    const float sec = (raw[p] + raw[(j << 7) | i]) * (0.5f / (TE * 10.0f));
    float v = fabsf(S * (1.0f / DD) - sec);

#pragma unroll
    for (int off = 32; off > 0; off >>= 1) v += __shfl_down(v, off);

    __shared__ float ls[4];
    const int tid = threadIdx.x;
    if ((tid & 63) == 0) ls[tid >> 6] = v;
    __syncthreads();
    if (tid == 0)
        atomicAdd(out, (ls[0] + ls[1] + ls[2] + ls[3]) * (1.0f / (NN * NN)));
}

extern "C" void kernel_launch(void* const* d_in, const int* in_sizes, int n_in,
                              void* d_out, int out_size, void* d_ws, size_t ws_size,
                              hipStream_t stream) {
    // inputs (setup_inputs order): merged, y_pred_i, y_pred_ij, input1, samples, labels
    const float* y_pred_i  = (const float*)d_in[1];
    const float* y_pred_ij = (const float*)d_in[2];
    const float* input1    = (const float*)d_in[3];
    const float* samples   = (const float*)d_in[4];
    float* out = (float*)d_out;

    // workspace layout: raw (N*N floats) only
    float* raw = (float*)d_ws;

    pair_all<<<1024, 256, 0, stream>>>(y_pred_ij, y_pred_i, input1, raw, out);
    finalize<<<64, 256, 0, stream>>>(raw, samples, out);
}

// Round 8
// 155.696 us; speedup vs baseline: 1.0501x; 1.0501x over previous
//
#include <hip/hip_runtime.h>

#define NN 128
#define TT 256
#define EE 6
#define DD 10
#define TE (TT*EE)          // 1536
#define C1 15               // input1 inner dim: 1+E+E+2

typedef float f32x4 __attribute__((ext_vector_type(4)));

// Fused pair kernel (best-verified r6 structure): each wave owns 4 tiles
// (i0..i0+3, j) = 24 KB of yij stream. w[j] and yi[j] live in REGISTERS
// (24 w + 24 yi floats per lane) -> no LDS, no barrier. 1024 blocks x 4 waves;
// all waves of a block share j (L1 reuse), and all 8 blocks sharing j land on
// one XCD (128 % 8 == 0) so yi/input1 are single-L2-resident. The 24 NT loads
// per wave are independent and hoistable by the compiler -> deep MLP.
__global__ __launch_bounds__(256) void pair_all(const float* __restrict__ yij,
                                                const float* __restrict__ yi,
                                                const float* __restrict__ input1,
                                                float* __restrict__ raw,
                                                float* __restrict__ out) {
    const int bid  = blockIdx.x;            // 0..1023
    const int tid  = threadIdx.x;
    const int lane = tid & 63;
    const int wv   = tid >> 6;
    const int j    = bid & (NN - 1);
    const int i0   = (bid >> 7) * 16 + wv * 4;     // {0,4,...,124}

    if (bid == 0 && tid == 0) out[0] = 0.0f;       // finalize runs in a later dispatch

    // Register prologue: this lane's 24 slots are float indices 4*lane + c + 256*k.
    f32x4 wj[6], mj[6];
    const float* __restrict__ i1 = input1 + (size_t)j * TT * C1 + 1 + EE;  // [t*C1 + e]
#pragma unroll
    for (int k = 0; k < 6; ++k) {
        mj[k] = *(const f32x4*)(yi + (size_t)j * TE + 4 * lane + 256 * k);
        f32x4 t;
#pragma unroll
        for (int c = 0; c < 4; ++c) {
            const int idx = 4 * lane + c + 256 * k;        // < 1536
            const int tt  = idx / EE, e = idx - tt * EE;   // const-div -> magic mul
            const float v = i1[tt * C1 + e];
            t[c] = 1.0f / (v * v);
        }
        wj[k] = t;
    }

    // Stream 4 tiles of 6 KB each, non-temporal (zero reuse).
    float accs[4];
#pragma unroll
    for (int p = 0; p < 4; ++p) {
        const f32x4* __restrict__ a =
            (const f32x4*)(yij + ((size_t)(i0 + p) * NN + j) * TE);
        float s0 = 0.0f, s1 = 0.0f, s2 = 0.0f, s3 = 0.0f;
#pragma unroll
        for (int k = 0; k < 6; ++k) {
            f32x4 x = __builtin_nontemporal_load(&a[lane + 64 * k]);
            float d0 = x.x - mj[k].x; s0 += d0 * d0 * wj[k].x;
            float d1 = x.y - mj[k].y; s1 += d1 * d1 * wj[k].y;
            float d2 = x.z - mj[k].z; s2 += d2 * d2 * wj[k].z;
            float d3 = x.w - mj[k].w; s3 += d3 * d3 * wj[k].w;
        }
        accs[p] = (s0 + s1) + (s2 + s3);
    }

#pragma unroll
    for (int p = 0; p < 4; ++p) {
        float s = accs[p];
#pragma unroll
        for (int off = 32; off > 0; off >>= 1) s += __shfl_down(s, off);
        if (lane == 0) raw[(i0 + p) * NN + j] = s;
    }
}

// Kernel 2: L = mean_{i,j} | S_ij - 0.5*(sec[i,j]+sec[j,i]) |
// 64 blocks x 256 threads; one scaled atomicAdd per block (out pre-zeroed by pair_all).
__global__ __launch_bounds__(256) void finalize(const float* __restrict__ raw,
                                                const float* __restrict__ samples,
                                                float* __restrict__ out) {
    __shared__ float smp[DD * NN];     // transposed: smp[d*NN + n], stride-1 reads
    for (int k = threadIdx.x; k < NN * DD; k += 256) {
        int n = k / DD, d = k % DD;
        smp[d * NN + n] = samples[k];
    }
    __syncthreads();

    const int p = blockIdx.x * 256 + threadIdx.x;   // 0..16383
    const int i = p >> 7, j = p & (NN - 1);

    float S = 0.0f;
#pragma unroll
    for (int d = 0; d < DD; ++d) {
        float dd = smp[d * NN + j] - smp[d * NN + i];
        S += dd * dd;
    }
    const float sec = (raw[p] + raw[(j << 7) | i]) * (0.5f / (TE * 10.0f));
    float v = fabsf(S * (1.0f / DD) - sec);

#pragma unroll
    for (int off = 32; off > 0; off >>= 1) v += __shfl_down(v, off);

    __shared__ float ls[4];
    const int tid = threadIdx.x;
    if ((tid & 63) == 0) ls[tid >> 6] = v;
    __syncthreads();
    if (tid == 0)
        atomicAdd(out, (ls[0] + ls[1] + ls[2] + ls[3]) * (1.0f / (NN * NN)));
}

extern "C" void kernel_launch(void* const* d_in, const int* in_sizes, int n_in,
                              void* d_out, int out_size, void* d_ws, size_t ws_size,
                              hipStream_t stream) {
    // inputs (setup_inputs order): merged, y_pred_i, y_pred_ij, input1, samples, labels
    const float* y_pred_i  = (const float*)d_in[1];
    const float* y_pred_ij = (const float*)d_in[2];
    const float* input1    = (const float*)d_in[3];
    const float* samples   = (const float*)d_in[4];
    float* out = (float*)d_out;

    // workspace layout: raw (N*N floats) only
    float* raw = (float*)d_ws;

    pair_all<<<1024, 256, 0, stream>>>(y_pred_ij, y_pred_i, input1, raw, out);
    finalize<<<64, 256, 0, stream>>>(raw, samples, out);
}